// Round 7
// baseline (8919.821 us; speedup 1.0000x reference)
//
#include <hip/hip_runtime.h>

// CustomLSTM on MI355X: persistent cooperative kernel, full-K waves (no reduce
// exchange), Wh0/Wh1 pinned in VGPRs, x@Wx0 hoisted (xg pre-GEMM), tree barrier.

#define NBLK 256
#define TPB  512
#define T_   512
#define HS_OFF 33554432   // outputs floats
#define CS_OFF 33685504   // HS_OFF + 2*64*1024

typedef float  f32x4  __attribute__((ext_vector_type(4)));
typedef short  bf16x8 __attribute__((ext_vector_type(8)));

// ---- workspace byte offsets ----
#define WS_CTR  0u              // 40960: gctr[8][1024] | rctr[1024] | flag[1024]
#define WS_W    40960u          // 4 * (4096*1024) bf16 = 32 MiB (permuted, [m][p][k])
#define WS_BIAS 33595392u       // 2*4096 f32
#define WS_XB   33628160u       // [T][B][D] bf16 = 64 MiB
#define WS_H0   100737024u      // ring: 2 * [64][1024] bf16
#define WS_H1   100999168u
#define WS_MIN  101261312u      // minimum ws (no xg)
#define WS_XG   101261312u      // [T][256][4][64][4] bf16 = 256 MiB
#define WS_BIG  369696768u

__device__ __forceinline__ unsigned short f2bf(float f) {
  union { float f; unsigned u; } v; v.f = f;
  return (unsigned short)((v.u + 0x7FFFu + ((v.u >> 16) & 1u)) >> 16);
}
__device__ __forceinline__ float bf2f(unsigned short s) {
  union { unsigned u; float f; } v; v.u = ((unsigned)s) << 16;
  return v.f;
}
__device__ __forceinline__ float fsig(float x) { return 1.0f / (1.0f + __expf(-x)); }
__device__ __forceinline__ float ftanh(float x) {
  x = fminf(15.0f, fmaxf(-15.0f, x));
  float e = __expf(2.0f * x);
  return (e - 1.0f) / (e + 1.0f);
}

// Permute+transpose+bf16 the 4 weight matrices: out[m][p][k] = bf16(W_m[k][orig(p)]),
// orig(p) = (p&3)*1024 + (p>>2)  (p = 4*j + gate). 64x64 tiles via LDS.
__global__ void kw(const float* __restrict__ Wx0, const float* __restrict__ Wh0,
                   const float* __restrict__ Wx1, const float* __restrict__ Wh1,
                   unsigned short* __restrict__ wp) {
  __shared__ float tile[64][65];
  int tb = blockIdx.x;
  int m  = tb >> 10;
  int kt = (tb >> 6) & 15;
  int nt = tb & 63;
  const float* W = (m == 0) ? Wx0 : (m == 1) ? Wh0 : (m == 2) ? Wx1 : Wh1;
  unsigned short* O = wp + (size_t)m * 4194304u;
  int k0 = kt * 64, n0 = nt * 64;
  int tx = threadIdx.x & 63, tg = threadIdx.x >> 6;
  for (int r = tg; r < 64; r += 4)
    tile[r][tx] = W[(size_t)(k0 + r) * 4096 + n0 + tx];
  __syncthreads();
  for (int r = tg; r < 64; r += 4) {
    int n = n0 + r;
    int p = ((n & 1023) << 2) | (n >> 10);
    O[(size_t)p * 1024 + k0 + tx] = f2bf(tile[tx][r]);
  }
}

// x [B][T][D] f32 -> xb [T*B][D] bf16 (row = t*64+b)
__global__ void kx(const float* __restrict__ x, unsigned short* __restrict__ xb) {
  int row = blockIdx.x;
  int t = row >> 6, b = row & 63;
  const float4* src = (const float4*)(x + ((size_t)b * 512 + t) * 1024);
  float4 f = src[threadIdx.x];
  ushort4 o; o.x = f2bf(f.x); o.y = f2bf(f.y); o.z = f2bf(f.z); o.w = f2bf(f.w);
  ((ushort4*)(xb + (size_t)row * 1024))[threadIdx.x] = o;
}

// bias permute + prime ring slot 1 with initial h states (bf16)
__global__ void kmisc(const float* __restrict__ b0, const float* __restrict__ b1,
                      const float* __restrict__ h0in,
                      float* __restrict__ biasP,
                      unsigned short* __restrict__ h0r, unsigned short* __restrict__ h1r) {
  int idx = blockIdx.x * 256 + threadIdx.x;
  if (idx < 8192) {
    int layer = idx >> 12, p = idx & 4095;
    int orig = (p & 3) * 1024 + (p >> 2);
    biasP[idx] = (layer ? b1 : b0)[orig];
  } else if (idx < 139264) {
    int e = idx - 8192;
    int layer = e >> 16, o = e & 65535;
    unsigned short v = f2bf(h0in[layer * 65536 + o]);
    if (layer) h1r[65536 + o] = v; else h0r[65536 + o] = v;
  }
}

// Pre-GEMM: xg[t][cb16][rt][lane][v] = (x[t] @ Wx0) fragment, finalize-lane layout.
// 2048 blocks = 128 col-blocks(32 cols) x 16 t-chunks(32 t). 8 waves = 4 rt x 2 kh.
__global__ void __launch_bounds__(512, 2)
kxg(const unsigned short* __restrict__ wp, const unsigned short* __restrict__ xb,
    unsigned short* __restrict__ xg) {
  __shared__ char sm[73728];                 // 64KB Wx0 slice + 8KB red
  float* red = (float*)(sm + 65536);
  const int tid = threadIdx.x;
  const int w = tid >> 6, l = tid & 63;
  const int cb = blockIdx.x >> 4;            // 32-col block, 0..127
  const int tc = blockIdx.x & 15;
  const int rt = w & 3, kh = w >> 2;

  const char* src = (const char*)(wp + (size_t)(cb * 32) * 1024u);
  for (int i = tid; i < 4096; i += 512) {
    int sb = i << 4;
    int c  = sb >> 11;
    int kb = sb & 2047;
    *(uint4*)(sm + (c << 11) + (kb ^ ((c & 7) << 4))) = *(const uint4*)(src + sb);
  }
  __syncthreads();

  const int ae0 = (rt * 16 + (l & 15)) * 1024 + kh * 512 + (l >> 4) * 8;
  const int kb2 = kh * 1024 + (l >> 4) * 16;
  const int swz = (l & 7) << 4;
  const int lb0 = (l & 15) << 11;
  const int lb1 = ((l & 15) + 16) << 11;

  for (int t = tc * 32; t < tc * 32 + 32; ++t) {
    const unsigned short* xt = xb + (size_t)t * 65536u;
    f32x4 a0 = {0.f, 0.f, 0.f, 0.f};
    f32x4 a1 = {0.f, 0.f, 0.f, 0.f};
    #pragma unroll
    for (int kk = 0; kk < 16; ++kk) {
      bf16x8 ax = *(const bf16x8*)(xt + ae0 + kk * 32);
      const int kb = (kb2 + kk * 64) ^ swz;
      bf16x8 b0 = *(const bf16x8*)(sm + lb0 + kb);
      bf16x8 b1 = *(const bf16x8*)(sm + lb1 + kb);
      a0 = __builtin_amdgcn_mfma_f32_16x16x32_bf16(ax, b0, a0, 0, 0, 0);
      a1 = __builtin_amdgcn_mfma_f32_16x16x32_bf16(ax, b1, a1, 0, 0, 0);
    }
    if (kh == 1) {
      float* r0 = red + (size_t)((rt * 2 + 0) * 64 + l) * 4;
      float* r1 = red + (size_t)((rt * 2 + 1) * 64 + l) * 4;
      #pragma unroll
      for (int v = 0; v < 4; ++v) { r0[v] = a0[v]; r1[v] = a1[v]; }
    }
    __syncthreads();
    if (kh == 0) {
      const float* r0 = red + (size_t)((rt * 2 + 0) * 64 + l) * 4;
      const float* r1 = red + (size_t)((rt * 2 + 1) * 64 + l) * 4;
      ushort4 o0, o1;
      o0.x = f2bf(a0[0] + r0[0]); o0.y = f2bf(a0[1] + r0[1]);
      o0.z = f2bf(a0[2] + r0[2]); o0.w = f2bf(a0[3] + r0[3]);
      o1.x = f2bf(a1[0] + r1[0]); o1.y = f2bf(a1[1] + r1[1]);
      o1.z = f2bf(a1[2] + r1[2]); o1.w = f2bf(a1[3] + r1[3]);
      *(ushort4*)(xg + ((((size_t)t * 256 + (cb * 2 + 0)) * 4 + rt) * 64 + l) * 4) = o0;
      *(ushort4*)(xg + ((((size_t)t * 256 + (cb * 2 + 1)) * 4 + rt) * 64 + l) * 4) = o1;
    }
    __syncthreads();
  }
}

// Persistent cooperative kernel. 256 blocks x 512 threads (8 waves).
// Wave w: layer (w>>2), row-tile (w&3), FULL K=1024 (no partial exchange).
// Wh0/Wh1 B-fragments pinned in VGPRs; Wx1 (and Wx0 fallback) from LDS.
__global__ void __launch_bounds__(TPB, 2)
klstm(const float* __restrict__ c0_in,
      const unsigned short* __restrict__ wp,
      const float* __restrict__ biasP,
      const unsigned short* __restrict__ xb,
      const unsigned short* __restrict__ xg,
      unsigned short* __restrict__ h0ring,
      unsigned short* __restrict__ h1ring,
      unsigned* __restrict__ ctrbase,
      float* __restrict__ out,
      int use_xg) {
  __shared__ char smem[65536];             // 32KB Wx1 slice (+32KB Wx0 fallback)
  unsigned* gctr = ctrbase;                // [8][1024]
  unsigned* rctr = ctrbase + 8192;         // [1024]
  unsigned* flag = ctrbase + 9216;         // [1024]
  const int tid = threadIdx.x;
  const int w   = tid >> 6;
  const int l   = tid & 63;
  const int bid = blockIdx.x;
  const int n0  = bid * 16;
  const int lay   = w >> 2;
  const int rbase = (w & 3) * 16;

  // stage Wx1 (m=2) at 0; Wx0 (m=0) at 32K only in fallback mode
  {
    const char* src = (const char*)(wp + 2u * 4194304u + (size_t)n0 * 1024u);
    for (int i = tid; i < 2048; i += TPB) {
      int sb = i << 4;
      int c  = sb >> 11;
      int kb = sb & 2047;
      *(uint4*)(smem + (c << 11) + (kb ^ ((c & 7) << 4))) = *(const uint4*)(src + sb);
    }
    if (!use_xg) {
      const char* s0 = (const char*)(wp + (size_t)n0 * 1024u);
      for (int i = tid; i < 2048; i += TPB) {
        int sb = i << 4;
        int c  = sb >> 11;
        int kb = sb & 2047;
        *(uint4*)(smem + 32768 + (c << 11) + (kb ^ ((c & 7) << 4))) = *(const uint4*)(s0 + sb);
      }
    }
  }

  // pin this wave's Wh (Wh0 for L0, Wh1 for L1) fragments: 32 x bf16x8 = 128 VGPR
  bf16x8 whf[32];
  {
    const unsigned short* pw_ = wp + (size_t)(lay ? 3u : 1u) * 4194304u
                              + (size_t)(n0 + (l & 15)) * 1024u + ((l >> 4) * 8);
    #pragma unroll
    for (int ks = 0; ks < 32; ++ks) whf[ks] = *(const bf16x8*)(pw_ + ks * 32);
  }

  const int jg = bid * 4 + ((l & 15) >> 2);   // global h column
  const float biasv = biasP[lay * 4096 + n0 + (l & 15)];
  const int qb = l & ~3;

  float cr[4];
  #pragma unroll
  for (int v = 0; v < 4; ++v)
    cr[v] = c0_in[lay * 65536 + (rbase + (l >> 4) * 4 + v) * 1024 + jg];
  __syncthreads();

  const int ae0 = (rbase + (l & 15)) * 1024 + (l >> 4) * 8;
  const int lb0 = (l & 15) << 11;
  const int kb0 = (l >> 4) * 16;
  const int swz = (l & 7) << 4;

  float xgf[4] = {0.f, 0.f, 0.f, 0.f};
  if (use_xg && lay == 0) {
    ushort4 xv = *(const ushort4*)(xg + (((size_t)0 * 256 + bid) * 4 + w) * 256 + (size_t)l * 4);
    xgf[0] = bf2f(xv.x); xgf[1] = bf2f(xv.y); xgf[2] = bf2f(xv.z); xgf[3] = bf2f(xv.w);
  }

  float hv[4] = {0.f, 0.f, 0.f, 0.f};

  for (int k = 0; k <= T_; ++k) {
    // ---- wait barrier(k-1) + acquire ----
    if (k > 0) {
      if (tid == 0) {
        unsigned spins = 0;
        while (__hip_atomic_load(&flag[k - 1], __ATOMIC_RELAXED, __HIP_MEMORY_SCOPE_AGENT) == 0u) {
          __builtin_amdgcn_s_sleep(1);
          if (++spins > 67108864u) break;   // safety: never wedge the GPU
        }
        __builtin_amdgcn_fence(__ATOMIC_ACQUIRE, "agent");
      }
      __syncthreads();
    }

    const unsigned short* h0p = h0ring + ((k + 1) & 1) * 65536;
    const unsigned short* h1p = h1ring + (k & 1) * 65536;
    const bool act = lay ? (k >= 1) : (k < T_);

    if (act) {
      f32x4 a0 = {0.f,0.f,0.f,0.f}, a1 = {0.f,0.f,0.f,0.f};
      f32x4 a2 = {0.f,0.f,0.f,0.f}, a3 = {0.f,0.f,0.f,0.f};
      if (lay == 0) {
        #pragma unroll
        for (int kk = 0; kk < 32; kk += 4) {
          bf16x8 h_0 = *(const bf16x8*)(h0p + ae0 + kk * 32);
          bf16x8 h_1 = *(const bf16x8*)(h0p + ae0 + kk * 32 + 32);
          bf16x8 h_2 = *(const bf16x8*)(h0p + ae0 + kk * 32 + 64);
          bf16x8 h_3 = *(const bf16x8*)(h0p + ae0 + kk * 32 + 96);
          a0 = __builtin_amdgcn_mfma_f32_16x16x32_bf16(h_0, whf[kk],     a0, 0, 0, 0);
          a1 = __builtin_amdgcn_mfma_f32_16x16x32_bf16(h_1, whf[kk + 1], a1, 0, 0, 0);
          a2 = __builtin_amdgcn_mfma_f32_16x16x32_bf16(h_2, whf[kk + 2], a2, 0, 0, 0);
          a3 = __builtin_amdgcn_mfma_f32_16x16x32_bf16(h_3, whf[kk + 3], a3, 0, 0, 0);
        }
        if (!use_xg) {
          const unsigned short* xt = xb + (size_t)k * 65536u;
          #pragma unroll
          for (int kk = 0; kk < 32; kk += 2) {
            bf16x8 x_0 = *(const bf16x8*)(xt + ae0 + kk * 32);
            bf16x8 x_1 = *(const bf16x8*)(xt + ae0 + kk * 32 + 32);
            bf16x8 b_0 = *(const bf16x8*)(smem + 32768 + lb0 + ((kb0 + kk * 64) ^ swz));
            bf16x8 b_1 = *(const bf16x8*)(smem + 32768 + lb0 + ((kb0 + kk * 64 + 64) ^ swz));
            a0 = __builtin_amdgcn_mfma_f32_16x16x32_bf16(x_0, b_0, a0, 0, 0, 0);
            a1 = __builtin_amdgcn_mfma_f32_16x16x32_bf16(x_1, b_1, a1, 0, 0, 0);
          }
        }
      } else {
        #pragma unroll
        for (int kk = 0; kk < 32; kk += 2) {
          bf16x8 h0a = *(const bf16x8*)(h0p + ae0 + kk * 32);
          bf16x8 h0b = *(const bf16x8*)(h0p + ae0 + kk * 32 + 32);
          bf16x8 h1a = *(const bf16x8*)(h1p + ae0 + kk * 32);
          bf16x8 h1b = *(const bf16x8*)(h1p + ae0 + kk * 32 + 32);
          bf16x8 b_0 = *(const bf16x8*)(smem + lb0 + ((kb0 + kk * 64) ^ swz));
          bf16x8 b_1 = *(const bf16x8*)(smem + lb0 + ((kb0 + kk * 64 + 64) ^ swz));
          a0 = __builtin_amdgcn_mfma_f32_16x16x32_bf16(h0a, b_0, a0, 0, 0, 0);
          a1 = __builtin_amdgcn_mfma_f32_16x16x32_bf16(h0b, b_1, a1, 0, 0, 0);
          a2 = __builtin_amdgcn_mfma_f32_16x16x32_bf16(h1a, whf[kk],     a2, 0, 0, 0);
          a3 = __builtin_amdgcn_mfma_f32_16x16x32_bf16(h1b, whf[kk + 1], a3, 0, 0, 0);
        }
      }

      unsigned short* hw = lay ? (h1ring + ((k + 1) & 1) * 65536)
                               : (h0ring + (k & 1) * 65536);
      #pragma unroll
      for (int v = 0; v < 4; ++v) {
        float gv = a0[v] + a1[v] + a2[v] + a3[v] + biasv;
        if (lay == 0) gv += xgf[v];
        float gi = __shfl(gv, qb);
        float gf = __shfl(gv, qb | 1);
        float gn = __shfl(gv, qb | 2);
        float go = __shfl(gv, qb | 3);
        float i_ = fsig(gi), f_ = fsig(gf), n_ = ftanh(gn), o_ = fsig(go);
        float c = f_ * cr[v] + i_ * n_;
        cr[v] = c;
        float h = o_ * ftanh(c);
        hv[v] = h;
        if ((l & 3) == 0)
          __hip_atomic_store(&hw[(rbase + (l >> 4) * 4 + v) * 1024 + jg], f2bf(h),
                             __ATOMIC_RELAXED, __HIP_MEMORY_SCOPE_AGENT);
      }
    }

    // ---- barrier arrival (h-ring stores drained block-wide) ----
    if (k < T_) {
      __syncthreads();
      if (tid == 0) {
        unsigned old = __hip_atomic_fetch_add(&gctr[(bid >> 5) * 1024 + k], 1u,
                                              __ATOMIC_RELAXED, __HIP_MEMORY_SCOPE_AGENT);
        if (old == 31u) {
          unsigned oldr = __hip_atomic_fetch_add(&rctr[k], 1u,
                                                 __ATOMIC_RELAXED, __HIP_MEMORY_SCOPE_AGENT);
          if (oldr == 7u)
            __hip_atomic_store(&flag[k], 1u, __ATOMIC_RELAXED, __HIP_MEMORY_SCOPE_AGENT);
        }
      }
    }

    // ---- overlap window: out stores + next xg prefetch ----
    if (lay == 1) {
      if (act && (l & 3) == 0) {
        #pragma unroll
        for (int v = 0; v < 4; ++v) {
          int row = rbase + (l >> 4) * 4 + v;
          out[(size_t)row * 524288u + (size_t)(k - 1) * 1024u + jg] = hv[v];
          if (k == T_) out[HS_OFF + 65536 + row * 1024 + jg] = hv[v];
        }
      }
    } else {
      if (k == T_ - 1 && (l & 3) == 0) {
        #pragma unroll
        for (int v = 0; v < 4; ++v)
          out[HS_OFF + (rbase + (l >> 4) * 4 + v) * 1024 + jg] = hv[v];
      }
      if (use_xg && k + 1 < T_) {
        ushort4 xv = *(const ushort4*)(xg + (((size_t)(k + 1) * 256 + bid) * 4 + w) * 256 + (size_t)l * 4);
        xgf[0] = bf2f(xv.x); xgf[1] = bf2f(xv.y); xgf[2] = bf2f(xv.z); xgf[3] = bf2f(xv.w);
      }
    }
  }

  // final cell states
  if ((l & 3) == 0) {
    #pragma unroll
    for (int v = 0; v < 4; ++v)
      out[CS_OFF + lay * 65536 + (rbase + (l >> 4) * 4 + v) * 1024 + jg] = cr[v];
  }
}

extern "C" void kernel_launch(void* const* d_in, const int* in_sizes, int n_in,
                              void* d_out, int out_size, void* d_ws, size_t ws_size,
                              hipStream_t stream) {
  const float* x   = (const float*)d_in[0];
  const float* h0  = (const float*)d_in[1];
  const float* c0  = (const float*)d_in[2];
  const float* Wx0 = (const float*)d_in[3];
  const float* Wh0 = (const float*)d_in[4];
  const float* b0  = (const float*)d_in[5];
  const float* Wx1 = (const float*)d_in[6];
  const float* Wh1 = (const float*)d_in[7];
  const float* b1  = (const float*)d_in[8];
  float* out = (float*)d_out;
  char* ws = (char*)d_ws;
  if (ws_size < (size_t)WS_MIN) return;   // workspace too small -> fail loudly
  const int use_xg = (ws_size >= (size_t)WS_BIG) ? 1 : 0;

  unsigned* ctr       = (unsigned*)(ws + WS_CTR);
  unsigned short* wp  = (unsigned short*)(ws + WS_W);
  float* biasP        = (float*)(ws + WS_BIAS);
  unsigned short* xbp = (unsigned short*)(ws + WS_XB);
  unsigned short* h0r = (unsigned short*)(ws + WS_H0);
  unsigned short* h1r = (unsigned short*)(ws + WS_H1);
  unsigned short* xgp = (unsigned short*)(ws + WS_XG);

  (void)hipMemsetAsync(ctr, 0, 40960, stream);
  hipLaunchKernelGGL(kw,    dim3(4096),  dim3(256), 0, stream, Wx0, Wh0, Wx1, Wh1, wp);
  hipLaunchKernelGGL(kx,    dim3(32768), dim3(256), 0, stream, x, xbp);
  hipLaunchKernelGGL(kmisc, dim3(544),   dim3(256), 0, stream, b0, b1, h0, biasP, h0r, h1r);
  if (use_xg)
    hipLaunchKernelGGL(kxg, dim3(2048),  dim3(512), 0, stream, wp, xbp, xgp);

  const float* c0a = c0; const unsigned short* wpa = wp; const float* bpa = biasP;
  const unsigned short* xba = xbp; const unsigned short* xga = xgp;
  unsigned short* h0a = h0r; unsigned short* h1a = h1r;
  unsigned* ca = ctr; float* oa = out; int uxg = use_xg;
  void* args[] = {&c0a, &wpa, &bpa, &xba, &xga, &h0a, &h1a, &ca, &oa, &uxg};
  hipError_t e = hipLaunchCooperativeKernel((const void*)klstm, dim3(NBLK), dim3(TPB),
                                            args, 0, stream);
  if (e != hipSuccess) {
    hipLaunchKernelGGL(klstm, dim3(NBLK), dim3(TPB), 0, stream,
                       c0a, wpa, bpa, xba, xga, h0a, h1a, ca, oa, uxg);
  }
}

// Round 8
// 7296.734 us; speedup vs baseline: 1.2224x; 1.2224x over previous
//
#include <hip/hip_runtime.h>

// CustomLSTM on MI355X: persistent cooperative kernel (R6 skeleton: K-split
// waves + LDS partial exchange), x@Wx0 hoisted (xg), Wh0/Wh1 truly pinned in
// VGPRs (launch_bounds relaxed + keep-alive asm), 2-level tree barrier with
// per-group release flags.

#define NBLK 256
#define TPB  512
#define T_   512
#define HS_OFF 33554432   // outputs floats
#define CS_OFF 33685504   // HS_OFF + 2*64*1024

typedef float  f32x4  __attribute__((ext_vector_type(4)));
typedef short  bf16x8 __attribute__((ext_vector_type(8)));

// ---- workspace byte offsets ----
#define WS_CTR  0u              // 69632: gctr[8][1024] | rctr[1024] | gflag[8][1024]
#define WS_W    69632u          // 4 * (4096*1024) bf16 = 32 MiB (permuted, [m][p][k])
#define WS_BIAS 33624064u       // 2*4096 f32
#define WS_XB   33656832u       // [T][B][D] bf16 = 64 MiB
#define WS_H0   100765696u      // ring: 2 * [64][1024] bf16
#define WS_H1   101027840u
#define WS_MIN  101289984u      // minimum ws (no xg)
#define WS_XG   101289984u      // [T][256][4][64][4] bf16 = 256 MiB
#define WS_BIG  369725440u

__device__ __forceinline__ unsigned short f2bf(float f) {
  union { float f; unsigned u; } v; v.f = f;
  return (unsigned short)((v.u + 0x7FFFu + ((v.u >> 16) & 1u)) >> 16);
}
__device__ __forceinline__ float bf2f(unsigned short s) {
  union { unsigned u; float f; } v; v.u = ((unsigned)s) << 16;
  return v.f;
}
__device__ __forceinline__ float fsig(float x) { return 1.0f / (1.0f + __expf(-x)); }
__device__ __forceinline__ float ftanh(float x) {
  x = fminf(15.0f, fmaxf(-15.0f, x));
  float e = __expf(2.0f * x);
  return (e - 1.0f) / (e + 1.0f);
}

// Permute+transpose+bf16 the 4 weight matrices: out[m][p][k] = bf16(W_m[k][orig(p)]),
// orig(p) = (p&3)*1024 + (p>>2)  (p = 4*j + gate). 64x64 tiles via LDS.
__global__ void kw(const float* __restrict__ Wx0, const float* __restrict__ Wh0,
                   const float* __restrict__ Wx1, const float* __restrict__ Wh1,
                   unsigned short* __restrict__ wp) {
  __shared__ float tile[64][65];
  int tb = blockIdx.x;
  int m  = tb >> 10;
  int kt = (tb >> 6) & 15;
  int nt = tb & 63;
  const float* W = (m == 0) ? Wx0 : (m == 1) ? Wh0 : (m == 2) ? Wx1 : Wh1;
  unsigned short* O = wp + (size_t)m * 4194304u;
  int k0 = kt * 64, n0 = nt * 64;
  int tx = threadIdx.x & 63, tg = threadIdx.x >> 6;
  for (int r = tg; r < 64; r += 4)
    tile[r][tx] = W[(size_t)(k0 + r) * 4096 + n0 + tx];
  __syncthreads();
  for (int r = tg; r < 64; r += 4) {
    int n = n0 + r;
    int p = ((n & 1023) << 2) | (n >> 10);
    O[(size_t)p * 1024 + k0 + tx] = f2bf(tile[tx][r]);
  }
}

// x [B][T][D] f32 -> xb [T*B][D] bf16 (row = t*64+b)
__global__ void kx(const float* __restrict__ x, unsigned short* __restrict__ xb) {
  int row = blockIdx.x;
  int t = row >> 6, b = row & 63;
  const float4* src = (const float4*)(x + ((size_t)b * 512 + t) * 1024);
  float4 f = src[threadIdx.x];
  ushort4 o; o.x = f2bf(f.x); o.y = f2bf(f.y); o.z = f2bf(f.z); o.w = f2bf(f.w);
  ((ushort4*)(xb + (size_t)row * 1024))[threadIdx.x] = o;
}

// bias permute + prime ring slot 1 with initial h states (bf16)
__global__ void kmisc(const float* __restrict__ b0, const float* __restrict__ b1,
                      const float* __restrict__ h0in,
                      float* __restrict__ biasP,
                      unsigned short* __restrict__ h0r, unsigned short* __restrict__ h1r) {
  int idx = blockIdx.x * 256 + threadIdx.x;
  if (idx < 8192) {
    int layer = idx >> 12, p = idx & 4095;
    int orig = (p & 3) * 1024 + (p >> 2);
    biasP[idx] = (layer ? b1 : b0)[orig];
  } else if (idx < 139264) {
    int e = idx - 8192;
    int layer = e >> 16, o = e & 65535;
    unsigned short v = f2bf(h0in[layer * 65536 + o]);
    if (layer) h1r[65536 + o] = v; else h0r[65536 + o] = v;
  }
}

// Pre-GEMM: xg[t][cb16][rt][lane][v] = (x[t] @ Wx0) fragment, finalize-lane layout.
// 2048 blocks = 128 col-blocks(32 cols) x 16 t-chunks(32 t). 8 waves = 4 rt x 2 kh.
__global__ void __launch_bounds__(512, 2)
kxg(const unsigned short* __restrict__ wp, const unsigned short* __restrict__ xb,
    unsigned short* __restrict__ xg) {
  __shared__ char sm[73728];                 // 64KB Wx0 slice + 8KB red
  float* red = (float*)(sm + 65536);
  const int tid = threadIdx.x;
  const int w = tid >> 6, l = tid & 63;
  const int cb = blockIdx.x >> 4;            // 32-col block, 0..127
  const int tc = blockIdx.x & 15;
  const int rt = w & 3, kh = w >> 2;

  const char* src = (const char*)(wp + (size_t)(cb * 32) * 1024u);
  for (int i = tid; i < 4096; i += 512) {
    int sb = i << 4;
    int c  = sb >> 11;
    int kb = sb & 2047;
    *(uint4*)(sm + (c << 11) + (kb ^ ((c & 7) << 4))) = *(const uint4*)(src + sb);
  }
  __syncthreads();

  const int ae0 = (rt * 16 + (l & 15)) * 1024 + kh * 512 + (l >> 4) * 8;
  const int kb2 = kh * 1024 + (l >> 4) * 16;
  const int swz = (l & 7) << 4;
  const int lb0 = (l & 15) << 11;
  const int lb1 = ((l & 15) + 16) << 11;

  for (int t = tc * 32; t < tc * 32 + 32; ++t) {
    const unsigned short* xt = xb + (size_t)t * 65536u;
    f32x4 a0 = {0.f, 0.f, 0.f, 0.f};
    f32x4 a1 = {0.f, 0.f, 0.f, 0.f};
    #pragma unroll
    for (int kk = 0; kk < 16; ++kk) {
      bf16x8 ax = *(const bf16x8*)(xt + ae0 + kk * 32);
      const int kb = (kb2 + kk * 64) ^ swz;
      bf16x8 b0 = *(const bf16x8*)(sm + lb0 + kb);
      bf16x8 b1 = *(const bf16x8*)(sm + lb1 + kb);
      a0 = __builtin_amdgcn_mfma_f32_16x16x32_bf16(ax, b0, a0, 0, 0, 0);
      a1 = __builtin_amdgcn_mfma_f32_16x16x32_bf16(ax, b1, a1, 0, 0, 0);
    }
    if (kh == 1) {
      float* r0 = red + (size_t)((rt * 2 + 0) * 64 + l) * 4;
      float* r1 = red + (size_t)((rt * 2 + 1) * 64 + l) * 4;
      #pragma unroll
      for (int v = 0; v < 4; ++v) { r0[v] = a0[v]; r1[v] = a1[v]; }
    }
    __syncthreads();
    if (kh == 0) {
      const float* r0 = red + (size_t)((rt * 2 + 0) * 64 + l) * 4;
      const float* r1 = red + (size_t)((rt * 2 + 1) * 64 + l) * 4;
      ushort4 o0, o1;
      o0.x = f2bf(a0[0] + r0[0]); o0.y = f2bf(a0[1] + r0[1]);
      o0.z = f2bf(a0[2] + r0[2]); o0.w = f2bf(a0[3] + r0[3]);
      o1.x = f2bf(a1[0] + r1[0]); o1.y = f2bf(a1[1] + r1[1]);
      o1.z = f2bf(a1[2] + r1[2]); o1.w = f2bf(a1[3] + r1[3]);
      *(ushort4*)(xg + ((((size_t)t * 256 + (cb * 2 + 0)) * 4 + rt) * 64 + l) * 4) = o0;
      *(ushort4*)(xg + ((((size_t)t * 256 + (cb * 2 + 1)) * 4 + rt) * 64 + l) * 4) = o1;
    }
    __syncthreads();
  }
}

// Persistent cooperative kernel. 256 blocks x 512 threads (8 waves).
// Wave w: rows 16*(w&3), K-half (w>>2)*512, finalizes layer (w>>2).
// Wh0/Wh1 B-fragments pinned in VGPRs (keep-alive asm); Wx0/Wx1 from LDS.
__global__ void __launch_bounds__(TPB)
klstm(const float* __restrict__ c0_in,
      const unsigned short* __restrict__ wp,
      const float* __restrict__ biasP,
      const unsigned short* __restrict__ xb,
      const unsigned short* __restrict__ xg,
      unsigned short* __restrict__ h0ring,
      unsigned short* __restrict__ h1ring,
      unsigned* __restrict__ ctrbase,
      float* __restrict__ out,
      int use_xg) {
  extern __shared__ char smem[];           // 96KB weight slots + 8KB reduce
  float* red = (float*)(smem + 131072);
  unsigned* gctr  = ctrbase;               // [8][1024]
  unsigned* rctr  = ctrbase + 8192;        // [1024]
  unsigned* gflag = ctrbase + 9216;        // [8][1024]
  const int tid = threadIdx.x;
  const int w   = tid >> 6;
  const int l   = tid & 63;
  const int bid = blockIdx.x;
  const int n0  = bid * 16;
  const int layer = w >> 2;
  const int rbase = (w & 3) * 16;
  const int khalf = (w >> 2) * 512;
  const int grp   = bid >> 5;

  // stage Wx0 (m=0) and Wx1 (m=2) slices into LDS, XOR-swizzled
  for (int m = 0; m < 4; m += 2) {
    const char* src = (const char*)(wp + (size_t)m * 4194304u + (size_t)n0 * 1024u);
    char* dst = smem + m * 32768;
    for (int i = tid; i < 2048; i += TPB) {
      int sb = i << 4;
      int c  = sb >> 11;
      int kb = sb & 2047;
      *(uint4*)(dst + (c << 11) + (kb ^ ((c & 7) << 4))) = *(const uint4*)(src + sb);
    }
  }

  // pin Wh0 / Wh1 fragments in VGPRs (16 cols x this wave's K-half)
  bf16x8 wh0f[16], wh1f[16];
  {
    const unsigned short* p0 = wp + 4194304u + (size_t)(n0 + (l & 15)) * 1024u + khalf + (l >> 4) * 8;
    const unsigned short* p1 = wp + 3u * 4194304u + (size_t)(n0 + (l & 15)) * 1024u + khalf + (l >> 4) * 8;
    #pragma unroll
    for (int ks = 0; ks < 16; ++ks) {
      wh0f[ks] = *(const bf16x8*)(p0 + ks * 32);
      wh1f[ks] = *(const bf16x8*)(p1 + ks * 32);
    }
  }

  const int jg = bid * 4 + ((l & 15) >> 2);   // global h column
  const float biasv = biasP[layer * 4096 + n0 + (l & 15)];
  const int qb = l & ~3;

  float cr[4];
  #pragma unroll
  for (int v = 0; v < 4; ++v)
    cr[v] = c0_in[layer * 65536 + (rbase + (l >> 4) * 4 + v) * 1024 + jg];
  __syncthreads();

  const int ae0  = (rbase + (l & 15)) * 1024 + khalf + (l >> 4) * 8;
  const int lb0  = (l & 15) << 11;
  const int kb2  = khalf * 2 + (l >> 4) * 16;
  const int swz  = (l & 7) << 4;

  for (int k = 0; k <= T_; ++k) {
    // force the pinned weight fragments to stay live in VGPRs (no remat/spill)
    #pragma unroll
    for (int ks = 0; ks < 16; ++ks) {
      asm volatile("" :: "v"(wh0f[ks]));
      asm volatile("" :: "v"(wh1f[ks]));
    }

    // xg fragment for this step (L0 finalize waves only)
    float xgf[4] = {0.f, 0.f, 0.f, 0.f};
    if (use_xg && w < 4 && k < T_) {
      ushort4 xv = *(const ushort4*)(xg + ((((size_t)k * 256 + bid) * 4 + w) * 64 + l) * 4);
      xgf[0] = bf2f(xv.x); xgf[1] = bf2f(xv.y); xgf[2] = bf2f(xv.z); xgf[3] = bf2f(xv.w);
    }

    const unsigned short* h0p = h0ring + ((k + 1) & 1) * 65536;
    const unsigned short* h1p = h1ring + (k & 1) * 65536;

    f32x4 acc0  = {0.f, 0.f, 0.f, 0.f};
    f32x4 acc0b = {0.f, 0.f, 0.f, 0.f};
    f32x4 acc1a = {0.f, 0.f, 0.f, 0.f};
    f32x4 acc1b = {0.f, 0.f, 0.f, 0.f};
    if (use_xg) {
      #pragma unroll
      for (int kk = 0; kk < 16; ++kk) {
        bf16x8 ah0 = *(const bf16x8*)(h0p + ae0 + kk * 32);
        bf16x8 ah1 = *(const bf16x8*)(h1p + ae0 + kk * 32);
        const int bo = lb0 + ((kb2 + kk * 64) ^ swz);
        bf16x8 bx1 = *(const bf16x8*)(smem + 65536 + bo);
        acc0  = __builtin_amdgcn_mfma_f32_16x16x32_bf16(ah0, wh0f[kk], acc0, 0, 0, 0);
        acc1a = __builtin_amdgcn_mfma_f32_16x16x32_bf16(ah0, bx1, acc1a, 0, 0, 0);
        acc1b = __builtin_amdgcn_mfma_f32_16x16x32_bf16(ah1, wh1f[kk], acc1b, 0, 0, 0);
      }
    } else {
      const unsigned short* xt = xb + (size_t)((k < T_) ? k : (T_ - 1)) * 65536u;
      #pragma unroll
      for (int kk = 0; kk < 16; ++kk) {
        bf16x8 ax  = *(const bf16x8*)(xt  + ae0 + kk * 32);
        bf16x8 ah0 = *(const bf16x8*)(h0p + ae0 + kk * 32);
        bf16x8 ah1 = *(const bf16x8*)(h1p + ae0 + kk * 32);
        const int bo = lb0 + ((kb2 + kk * 64) ^ swz);
        bf16x8 bx0 = *(const bf16x8*)(smem + bo);
        bf16x8 bx1 = *(const bf16x8*)(smem + 65536 + bo);
        acc0b = __builtin_amdgcn_mfma_f32_16x16x32_bf16(ax,  bx0, acc0b, 0, 0, 0);
        acc0  = __builtin_amdgcn_mfma_f32_16x16x32_bf16(ah0, wh0f[kk], acc0, 0, 0, 0);
        acc1a = __builtin_amdgcn_mfma_f32_16x16x32_bf16(ah0, bx1, acc1a, 0, 0, 0);
        acc1b = __builtin_amdgcn_mfma_f32_16x16x32_bf16(ah1, wh1f[kk], acc1b, 0, 0, 0);
      }
    }

    { // publish the other layer's partial for the partner wave
      float* rb = red + (size_t)(w * 64 + l) * 4;
      f32x4 other = layer ? (acc0 + acc0b) : (acc1a + acc1b);
      #pragma unroll
      for (int v = 0; v < 4; ++v) rb[v] = other[v];
    }
    __syncthreads();

    f32x4 g = layer ? (acc1a + acc1b) : (acc0 + acc0b);
    {
      const int pw = layer ? (w - 4) : (w + 4);
      const float* rb = red + (size_t)(pw * 64 + l) * 4;
      #pragma unroll
      for (int v = 0; v < 4; ++v) g[v] += rb[v];
    }
    if (use_xg && w < 4) {
      #pragma unroll
      for (int v = 0; v < 4; ++v) g[v] += xgf[v];
    }

    const bool active = layer ? (k >= 1) : (k < T_);
    float hv[4];
    if (active) {
      unsigned short* hw = layer ? (h1ring + ((k + 1) & 1) * 65536)
                                 : (h0ring + (k & 1) * 65536);
      #pragma unroll
      for (int v = 0; v < 4; ++v) {
        float gv = g[v] + biasv;
        float gi = __shfl(gv, qb);
        float gf = __shfl(gv, qb | 1);
        float gn = __shfl(gv, qb | 2);
        float go = __shfl(gv, qb | 3);
        float i_ = fsig(gi), f_ = fsig(gf), n_ = ftanh(gn), o_ = fsig(go);
        float c = f_ * cr[v] + i_ * n_;
        cr[v] = c;
        float h = o_ * ftanh(c);
        hv[v] = h;
        if ((l & 3) == 0)
          __hip_atomic_store(&hw[(rbase + (l >> 4) * 4 + v) * 1024 + jg], f2bf(h),
                             __ATOMIC_RELAXED, __HIP_MEMORY_SCOPE_AGENT);
      }
    }

    // ---- barrier arrival (h stores drained by syncthreads) ----
    if (k < T_) {
      __syncthreads();
      if (tid == 0) {
        unsigned old = __hip_atomic_fetch_add(&gctr[grp * 1024 + k], 1u,
                                              __ATOMIC_RELAXED, __HIP_MEMORY_SCOPE_AGENT);
        if (old == 31u) {
          unsigned oldr = __hip_atomic_fetch_add(&rctr[k], 1u,
                                                 __ATOMIC_RELAXED, __HIP_MEMORY_SCOPE_AGENT);
          if (oldr == 7u) {
            #pragma unroll
            for (int gg = 0; gg < 8; ++gg)
              __hip_atomic_store(&gflag[gg * 1024 + k], 1u,
                                 __ATOMIC_RELAXED, __HIP_MEMORY_SCOPE_AGENT);
          }
        }
      }
    }

    // ---- out stores overlapped with barrier propagation ----
    if (active && (l & 3) == 0) {
      #pragma unroll
      for (int v = 0; v < 4; ++v) {
        int row = rbase + (l >> 4) * 4 + v;
        if (layer) {
          out[(size_t)row * 524288u + (size_t)(k - 1) * 1024u + jg] = hv[v];
          if (k == T_) out[HS_OFF + 65536 + row * 1024 + jg] = hv[v];
        } else {
          if (k == T_ - 1) out[HS_OFF + row * 1024 + jg] = hv[v];
        }
      }
    }

    // ---- barrier wait (per-group flag line) + acquire ----
    if (k < T_) {
      if (tid == 0) {
        unsigned spins = 0;
        while (__hip_atomic_load(&gflag[grp * 1024 + k], __ATOMIC_RELAXED, __HIP_MEMORY_SCOPE_AGENT) == 0u) {
          __builtin_amdgcn_s_sleep(1);
          if (++spins > 67108864u) break;   // safety: never wedge the GPU
        }
        __builtin_amdgcn_fence(__ATOMIC_ACQUIRE, "agent");
      }
      __syncthreads();
    }
  }

  // final cell states
  if ((l & 3) == 0) {
    #pragma unroll
    for (int v = 0; v < 4; ++v)
      out[CS_OFF + layer * 65536 + (rbase + (l >> 4) * 4 + v) * 1024 + jg] = cr[v];
  }
}

extern "C" void kernel_launch(void* const* d_in, const int* in_sizes, int n_in,
                              void* d_out, int out_size, void* d_ws, size_t ws_size,
                              hipStream_t stream) {
  const float* x   = (const float*)d_in[0];
  const float* h0  = (const float*)d_in[1];
  const float* c0  = (const float*)d_in[2];
  const float* Wx0 = (const float*)d_in[3];
  const float* Wh0 = (const float*)d_in[4];
  const float* b0  = (const float*)d_in[5];
  const float* Wx1 = (const float*)d_in[6];
  const float* Wh1 = (const float*)d_in[7];
  const float* b1  = (const float*)d_in[8];
  float* out = (float*)d_out;
  char* ws = (char*)d_ws;
  if (ws_size < (size_t)WS_MIN) return;   // workspace too small -> fail loudly
  const int use_xg = (ws_size >= (size_t)WS_BIG) ? 1 : 0;

  unsigned* ctr       = (unsigned*)(ws + WS_CTR);
  unsigned short* wp  = (unsigned short*)(ws + WS_W);
  float* biasP        = (float*)(ws + WS_BIAS);
  unsigned short* xbp = (unsigned short*)(ws + WS_XB);
  unsigned short* h0r = (unsigned short*)(ws + WS_H0);
  unsigned short* h1r = (unsigned short*)(ws + WS_H1);
  unsigned short* xgp = (unsigned short*)(ws + WS_XG);

  (void)hipMemsetAsync(ctr, 0, 69632, stream);
  hipLaunchKernelGGL(kw,    dim3(4096),  dim3(256), 0, stream, Wx0, Wh0, Wx1, Wh1, wp);
  hipLaunchKernelGGL(kx,    dim3(32768), dim3(256), 0, stream, x, xbp);
  hipLaunchKernelGGL(kmisc, dim3(544),   dim3(256), 0, stream, b0, b1, h0, biasP, h0r, h1r);
  if (use_xg)
    hipLaunchKernelGGL(kxg, dim3(2048),  dim3(512), 0, stream, wp, xbp, xgp);

  (void)hipFuncSetAttribute((const void*)klstm, hipFuncAttributeMaxDynamicSharedMemorySize, 139264);
  const float* c0a = c0; const unsigned short* wpa = wp; const float* bpa = biasP;
  const unsigned short* xba = xbp; const unsigned short* xga = xgp;
  unsigned short* h0a = h0r; unsigned short* h1a = h1r;
  unsigned* ca = ctr; float* oa = out; int uxg = use_xg;
  void* args[] = {&c0a, &wpa, &bpa, &xba, &xga, &h0a, &h1a, &ca, &oa, &uxg};
  hipError_t e = hipLaunchCooperativeKernel((const void*)klstm, dim3(NBLK), dim3(TPB),
                                            args, 139264, stream);
  if (e != hipSuccess) {
    hipLaunchKernelGGL(klstm, dim3(NBLK), dim3(TPB), 139264, stream,
                       c0a, wpa, bpa, xba, xga, h0a, h1a, ca, oa, uxg);
  }
}

// Round 9
// 5899.999 us; speedup vs baseline: 1.5118x; 1.2367x over previous
//
#include <hip/hip_runtime.h>

// CustomLSTM on MI355X: persistent cooperative kernel (R6 skeleton), xg hoist,
// Wh in AGPR/VGPR, tree barrier; R9: blocked h-ring [blk][row][4] with
// LDS-repacked coalesced stores (8B h / 16B out) + pre-spin xg prefetch.

#define NBLK 256
#define TPB  512
#define T_   512
#define HS_OFF 33554432   // outputs floats
#define CS_OFF 33685504   // HS_OFF + 2*64*1024

typedef float  f32x4  __attribute__((ext_vector_type(4)));
typedef short  bf16x8 __attribute__((ext_vector_type(8)));

// ---- workspace byte offsets ----
#define WS_CTR  0u              // 69632: gctr[8][1024] | rctr[1024] | gflag[8][1024]
#define WS_W    69632u          // 4 * (4096*1024) bf16 = 32 MiB (permuted, [m][p][k])
#define WS_BIAS 33624064u       // 2*4096 f32
#define WS_XB   33656832u       // [T][B][D] bf16 = 64 MiB
#define WS_H0   100765696u      // ring: 2 * 65536 bf16, blocked [256][64][4]
#define WS_H1   101027840u
#define WS_MIN  101289984u      // minimum ws (no xg)
#define WS_XG   101289984u      // [T][256][4][64][4] bf16 = 256 MiB
#define WS_BIG  369725440u

__device__ __forceinline__ unsigned short f2bf(float f) {
  union { float f; unsigned u; } v; v.f = f;
  return (unsigned short)((v.u + 0x7FFFu + ((v.u >> 16) & 1u)) >> 16);
}
__device__ __forceinline__ float bf2f(unsigned short s) {
  union { unsigned u; float f; } v; v.u = ((unsigned)s) << 16;
  return v.f;
}
__device__ __forceinline__ float fsig(float x) { return 1.0f / (1.0f + __expf(-x)); }
__device__ __forceinline__ float ftanh(float x) {
  x = fminf(15.0f, fmaxf(-15.0f, x));
  float e = __expf(2.0f * x);
  return (e - 1.0f) / (e + 1.0f);
}

// blocked h-ring fragment load: 8 consecutive cols c0..c0+7 of row (row4 = row*4)
__device__ __forceinline__ bf16x8 ldh8(const unsigned short* ring, int c0, int row4) {
  const int b = (c0 >> 2) * 256 + row4;
  ushort4 lo = *(const ushort4*)(ring + b);
  ushort4 hi = *(const ushort4*)(ring + b + 256);
  bf16x8 r;
  r[0] = (short)lo.x; r[1] = (short)lo.y; r[2] = (short)lo.z; r[3] = (short)lo.w;
  r[4] = (short)hi.x; r[5] = (short)hi.y; r[6] = (short)hi.z; r[7] = (short)hi.w;
  return r;
}

// Permute+transpose+bf16 the 4 weight matrices: out[m][p][k] = bf16(W_m[k][orig(p)]),
// orig(p) = (p&3)*1024 + (p>>2)  (p = 4*j + gate). 64x64 tiles via LDS.
__global__ void kw(const float* __restrict__ Wx0, const float* __restrict__ Wh0,
                   const float* __restrict__ Wx1, const float* __restrict__ Wh1,
                   unsigned short* __restrict__ wp) {
  __shared__ float tile[64][65];
  int tb = blockIdx.x;
  int m  = tb >> 10;
  int kt = (tb >> 6) & 15;
  int nt = tb & 63;
  const float* W = (m == 0) ? Wx0 : (m == 1) ? Wh0 : (m == 2) ? Wx1 : Wh1;
  unsigned short* O = wp + (size_t)m * 4194304u;
  int k0 = kt * 64, n0 = nt * 64;
  int tx = threadIdx.x & 63, tg = threadIdx.x >> 6;
  for (int r = tg; r < 64; r += 4)
    tile[r][tx] = W[(size_t)(k0 + r) * 4096 + n0 + tx];
  __syncthreads();
  for (int r = tg; r < 64; r += 4) {
    int n = n0 + r;
    int p = ((n & 1023) << 2) | (n >> 10);
    O[(size_t)p * 1024 + k0 + tx] = f2bf(tile[tx][r]);
  }
}

// x [B][T][D] f32 -> xb [T*B][D] bf16 (row = t*64+b)
__global__ void kx(const float* __restrict__ x, unsigned short* __restrict__ xb) {
  int row = blockIdx.x;
  int t = row >> 6, b = row & 63;
  const float4* src = (const float4*)(x + ((size_t)b * 512 + t) * 1024);
  float4 f = src[threadIdx.x];
  ushort4 o; o.x = f2bf(f.x); o.y = f2bf(f.y); o.z = f2bf(f.z); o.w = f2bf(f.w);
  ((ushort4*)(xb + (size_t)row * 1024))[threadIdx.x] = o;
}

// bias permute + prime ring slot 1 with initial h states (bf16, BLOCKED layout)
__global__ void kmisc(const float* __restrict__ b0, const float* __restrict__ b1,
                      const float* __restrict__ h0in,
                      float* __restrict__ biasP,
                      unsigned short* __restrict__ h0r, unsigned short* __restrict__ h1r) {
  int idx = blockIdx.x * 256 + threadIdx.x;
  if (idx < 8192) {
    int layer = idx >> 12, p = idx & 4095;
    int orig = (p & 3) * 1024 + (p >> 2);
    biasP[idx] = (layer ? b1 : b0)[orig];
  } else if (idx < 139264) {
    int e = idx - 8192;
    int layer = e >> 16, o = e & 65535;
    int row = o >> 10, col = o & 1023;
    unsigned short v = f2bf(h0in[layer * 65536 + o]);
    int dst = 65536 + (col >> 2) * 256 + row * 4 + (col & 3);
    if (layer) h1r[dst] = v; else h0r[dst] = v;
  }
}

// Pre-GEMM: xg[t][cb16][rt][lane][v] = (x[t] @ Wx0) fragment, finalize-lane layout.
// 2048 blocks = 128 col-blocks(32 cols) x 16 t-chunks(32 t). 8 waves = 4 rt x 2 kh.
__global__ void __launch_bounds__(512, 2)
kxg(const unsigned short* __restrict__ wp, const unsigned short* __restrict__ xb,
    unsigned short* __restrict__ xg) {
  __shared__ char sm[73728];                 // 64KB Wx0 slice + 8KB red
  float* red = (float*)(sm + 65536);
  const int tid = threadIdx.x;
  const int w = tid >> 6, l = tid & 63;
  const int cb = blockIdx.x >> 4;            // 32-col block, 0..127
  const int tc = blockIdx.x & 15;
  const int rt = w & 3, kh = w >> 2;

  const char* src = (const char*)(wp + (size_t)(cb * 32) * 1024u);
  for (int i = tid; i < 4096; i += 512) {
    int sb = i << 4;
    int c  = sb >> 11;
    int kb = sb & 2047;
    *(uint4*)(sm + (c << 11) + (kb ^ ((c & 7) << 4))) = *(const uint4*)(src + sb);
  }
  __syncthreads();

  const int ae0 = (rt * 16 + (l & 15)) * 1024 + kh * 512 + (l >> 4) * 8;
  const int kb2 = kh * 1024 + (l >> 4) * 16;
  const int swz = (l & 7) << 4;
  const int lb0 = (l & 15) << 11;
  const int lb1 = ((l & 15) + 16) << 11;

  for (int t = tc * 32; t < tc * 32 + 32; ++t) {
    const unsigned short* xt = xb + (size_t)t * 65536u;
    f32x4 a0 = {0.f, 0.f, 0.f, 0.f};
    f32x4 a1 = {0.f, 0.f, 0.f, 0.f};
    #pragma unroll
    for (int kk = 0; kk < 16; ++kk) {
      bf16x8 ax = *(const bf16x8*)(xt + ae0 + kk * 32);
      const int kb = (kb2 + kk * 64) ^ swz;
      bf16x8 b0 = *(const bf16x8*)(sm + lb0 + kb);
      bf16x8 b1 = *(const bf16x8*)(sm + lb1 + kb);
      a0 = __builtin_amdgcn_mfma_f32_16x16x32_bf16(ax, b0, a0, 0, 0, 0);
      a1 = __builtin_amdgcn_mfma_f32_16x16x32_bf16(ax, b1, a1, 0, 0, 0);
    }
    if (kh == 1) {
      float* r0 = red + (size_t)((rt * 2 + 0) * 64 + l) * 4;
      float* r1 = red + (size_t)((rt * 2 + 1) * 64 + l) * 4;
      #pragma unroll
      for (int v = 0; v < 4; ++v) { r0[v] = a0[v]; r1[v] = a1[v]; }
    }
    __syncthreads();
    if (kh == 0) {
      const float* r0 = red + (size_t)((rt * 2 + 0) * 64 + l) * 4;
      const float* r1 = red + (size_t)((rt * 2 + 1) * 64 + l) * 4;
      ushort4 o0, o1;
      o0.x = f2bf(a0[0] + r0[0]); o0.y = f2bf(a0[1] + r0[1]);
      o0.z = f2bf(a0[2] + r0[2]); o0.w = f2bf(a0[3] + r0[3]);
      o1.x = f2bf(a1[0] + r1[0]); o1.y = f2bf(a1[1] + r1[1]);
      o1.z = f2bf(a1[2] + r1[2]); o1.w = f2bf(a1[3] + r1[3]);
      *(ushort4*)(xg + ((((size_t)t * 256 + (cb * 2 + 0)) * 4 + rt) * 64 + l) * 4) = o0;
      *(ushort4*)(xg + ((((size_t)t * 256 + (cb * 2 + 1)) * 4 + rt) * 64 + l) * 4) = o1;
    }
    __syncthreads();
  }
}

// Persistent cooperative kernel. 256 blocks x 512 threads (8 waves).
// Wave w: rows 16*(w&3), K-half (w>>2)*512, finalizes layer (w>>2).
__global__ void __launch_bounds__(TPB)
klstm(const float* __restrict__ c0_in,
      const unsigned short* __restrict__ wp,
      const float* __restrict__ biasP,
      const unsigned short* __restrict__ xb,
      const unsigned short* __restrict__ xg,
      unsigned short* __restrict__ h0ring,
      unsigned short* __restrict__ h1ring,
      unsigned* __restrict__ ctrbase,
      float* __restrict__ out,
      int use_xg) {
  extern __shared__ char smem[];           // 64KB Wx + 8KB red + 2KB h-repack
  float* red = (float*)(smem + 131072);
  float* lhb = (float*)(smem + 139264);
  unsigned* gctr  = ctrbase;               // [8][1024]
  unsigned* rctr  = ctrbase + 8192;        // [1024]
  unsigned* gflag = ctrbase + 9216;        // [8][1024]
  const int tid = threadIdx.x;
  const int w   = tid >> 6;
  const int l   = tid & 63;
  const int bid = blockIdx.x;
  const int n0  = bid * 16;
  const int layer = w >> 2;
  const int rbase = (w & 3) * 16;
  const int khalf = (w >> 2) * 512;
  const int grp   = bid >> 5;
  float* lh = lhb + w * 64;                // [16 rows][4 cols] f32 per wave

  // stage Wx0 (m=0) and Wx1 (m=2) slices into LDS, XOR-swizzled
  for (int m = 0; m < 4; m += 2) {
    const char* src = (const char*)(wp + (size_t)m * 4194304u + (size_t)n0 * 1024u);
    char* dst = smem + m * 32768;
    for (int i = tid; i < 2048; i += TPB) {
      int sb = i << 4;
      int c  = sb >> 11;
      int kb = sb & 2047;
      *(uint4*)(dst + (c << 11) + (kb ^ ((c & 7) << 4))) = *(const uint4*)(src + sb);
    }
  }

  // pin Wh0 / Wh1 fragments (16 cols x this wave's K-half)
  bf16x8 wh0f[16], wh1f[16];
  {
    const unsigned short* p0 = wp + 4194304u + (size_t)(n0 + (l & 15)) * 1024u + khalf + (l >> 4) * 8;
    const unsigned short* p1 = wp + 3u * 4194304u + (size_t)(n0 + (l & 15)) * 1024u + khalf + (l >> 4) * 8;
    #pragma unroll
    for (int ks = 0; ks < 16; ++ks) {
      wh0f[ks] = *(const bf16x8*)(p0 + ks * 32);
      wh1f[ks] = *(const bf16x8*)(p1 + ks * 32);
    }
  }

  const int jg = bid * 4 + ((l & 15) >> 2);   // global h column (gate finalize)
  const float biasv = biasP[layer * 4096 + n0 + (l & 15)];
  const int qb = l & ~3;

  float cr[4];
  #pragma unroll
  for (int v = 0; v < 4; ++v)
    cr[v] = c0_in[layer * 65536 + (rbase + (l >> 4) * 4 + v) * 1024 + jg];
  __syncthreads();

  const int ae0  = (rbase + (l & 15)) * 1024 + khalf + (l >> 4) * 8;  // xb (row-major)
  const int row4 = (rbase + (l & 15)) * 4;                            // blocked ring
  const int cb0  = khalf + (l >> 4) * 8;
  const int lb0  = (l & 15) << 11;
  const int kb2  = khalf * 2 + (l >> 4) * 16;
  const int swz  = (l & 7) << 4;

  float xgf[4] = {0.f, 0.f, 0.f, 0.f};
  if (use_xg && w < 4) {
    ushort4 xv = *(const ushort4*)(xg + (((size_t)bid * 4 + w) * 64 + l) * 4);
    xgf[0] = bf2f(xv.x); xgf[1] = bf2f(xv.y); xgf[2] = bf2f(xv.z); xgf[3] = bf2f(xv.w);
  }

  for (int k = 0; k <= T_; ++k) {
    #pragma unroll
    for (int ks = 0; ks < 16; ++ks) {
      asm volatile("" :: "v"(wh0f[ks]));
      asm volatile("" :: "v"(wh1f[ks]));
    }

    const unsigned short* h0p = h0ring + ((k + 1) & 1) * 65536;
    const unsigned short* h1p = h1ring + (k & 1) * 65536;

    f32x4 acc0  = {0.f, 0.f, 0.f, 0.f};
    f32x4 acc0b = {0.f, 0.f, 0.f, 0.f};
    f32x4 acc1a = {0.f, 0.f, 0.f, 0.f};
    f32x4 acc1b = {0.f, 0.f, 0.f, 0.f};
    if (use_xg) {
      #pragma unroll
      for (int kk = 0; kk < 16; ++kk) {
        const int c0 = cb0 + kk * 32;
        bf16x8 ah0 = ldh8(h0p, c0, row4);
        bf16x8 ah1 = ldh8(h1p, c0, row4);
        const int bo = lb0 + ((kb2 + kk * 64) ^ swz);
        bf16x8 bx1 = *(const bf16x8*)(smem + 65536 + bo);
        acc0  = __builtin_amdgcn_mfma_f32_16x16x32_bf16(ah0, wh0f[kk], acc0, 0, 0, 0);
        acc1a = __builtin_amdgcn_mfma_f32_16x16x32_bf16(ah0, bx1, acc1a, 0, 0, 0);
        acc1b = __builtin_amdgcn_mfma_f32_16x16x32_bf16(ah1, wh1f[kk], acc1b, 0, 0, 0);
      }
    } else {
      const unsigned short* xt = xb + (size_t)((k < T_) ? k : (T_ - 1)) * 65536u;
      #pragma unroll
      for (int kk = 0; kk < 16; ++kk) {
        const int c0 = cb0 + kk * 32;
        bf16x8 ax  = *(const bf16x8*)(xt + ae0 + kk * 32);
        bf16x8 ah0 = ldh8(h0p, c0, row4);
        bf16x8 ah1 = ldh8(h1p, c0, row4);
        const int bo = lb0 + ((kb2 + kk * 64) ^ swz);
        bf16x8 bx0 = *(const bf16x8*)(smem + bo);
        bf16x8 bx1 = *(const bf16x8*)(smem + 65536 + bo);
        acc0b = __builtin_amdgcn_mfma_f32_16x16x32_bf16(ax,  bx0, acc0b, 0, 0, 0);
        acc0  = __builtin_amdgcn_mfma_f32_16x16x32_bf16(ah0, wh0f[kk], acc0, 0, 0, 0);
        acc1a = __builtin_amdgcn_mfma_f32_16x16x32_bf16(ah0, bx1, acc1a, 0, 0, 0);
        acc1b = __builtin_amdgcn_mfma_f32_16x16x32_bf16(ah1, wh1f[kk], acc1b, 0, 0, 0);
      }
    }

    { // publish the other layer's partial for the partner wave
      float* rb = red + (size_t)(w * 64 + l) * 4;
      f32x4 other = layer ? (acc0 + acc0b) : (acc1a + acc1b);
      #pragma unroll
      for (int v = 0; v < 4; ++v) rb[v] = other[v];
    }
    __syncthreads();

    f32x4 g = layer ? (acc1a + acc1b) : (acc0 + acc0b);
    {
      const int pw = layer ? (w - 4) : (w + 4);
      const float* rb = red + (size_t)(pw * 64 + l) * 4;
      #pragma unroll
      for (int v = 0; v < 4; ++v) g[v] += rb[v];
    }
    if (use_xg && w < 4) {
      #pragma unroll
      for (int v = 0; v < 4; ++v) g[v] += xgf[v];
    }

    const bool active = layer ? (k >= 1) : (k < T_);
    f32x4 outv = {0.f, 0.f, 0.f, 0.f};
    if (active) {
      unsigned short* hw = layer ? (h1ring + ((k + 1) & 1) * 65536)
                                 : (h0ring + (k & 1) * 65536);
      #pragma unroll
      for (int v = 0; v < 4; ++v) {
        float gv = g[v] + biasv;
        float gi = __shfl(gv, qb);
        float gf = __shfl(gv, qb | 1);
        float gn = __shfl(gv, qb | 2);
        float go = __shfl(gv, qb | 3);
        float i_ = fsig(gi), f_ = fsig(gf), n_ = ftanh(gn), o_ = fsig(go);
        float c = f_ * cr[v] + i_ * n_;
        cr[v] = c;
        float h = o_ * ftanh(c);
        if ((l & 3) == 0)
          lh[((l >> 4) * 4 + v) * 4 + ((l & 15) >> 2)] = h;   // repack tile
      }
      if (l < 16) {   // same-wave read-back: coalesced 8B agent store
        f32x4 h4 = *(f32x4*)(lh + l * 4);
        outv = h4;
        ushort4 u4;
        u4.x = f2bf(h4[0]); u4.y = f2bf(h4[1]); u4.z = f2bf(h4[2]); u4.w = f2bf(h4[3]);
        union { ushort4 s; unsigned long long q; } pk; pk.s = u4;
        __hip_atomic_store((unsigned long long*)(hw + bid * 256 + (rbase + l) * 4), pk.q,
                           __ATOMIC_RELAXED, __HIP_MEMORY_SCOPE_AGENT);
      }
    }

    // ---- barrier arrival (h stores drained by syncthreads) ----
    if (k < T_) {
      __syncthreads();
      if (tid == 0) {
        unsigned old = __hip_atomic_fetch_add(&gctr[grp * 1024 + k], 1u,
                                              __ATOMIC_RELAXED, __HIP_MEMORY_SCOPE_AGENT);
        if (old == 31u) {
          unsigned oldr = __hip_atomic_fetch_add(&rctr[k], 1u,
                                                 __ATOMIC_RELAXED, __HIP_MEMORY_SCOPE_AGENT);
          if (oldr == 7u) {
            #pragma unroll
            for (int gg = 0; gg < 8; ++gg)
              __hip_atomic_store(&gflag[gg * 1024 + k], 1u,
                                 __ATOMIC_RELAXED, __HIP_MEMORY_SCOPE_AGENT);
          }
        }
      }
    }

    // ---- overlap window: deferred out stores + next-step xg prefetch ----
    if (active && l < 16) {
      const int row = rbase + l;
      if (layer) {
        *(f32x4*)(out + (size_t)row * 524288u + (size_t)(k - 1) * 1024u + bid * 4) = outv;
        if (k == T_)
          *(f32x4*)(out + HS_OFF + 65536 + row * 1024 + bid * 4) = outv;
      } else if (k == T_ - 1) {
        *(f32x4*)(out + HS_OFF + row * 1024 + bid * 4) = outv;
      }
    }
    if (use_xg && w < 4 && k + 1 < T_) {   // registers survive the acquire-inv
      ushort4 xv = *(const ushort4*)(xg + ((((size_t)(k + 1) * 256 + bid) * 4 + w) * 64 + l) * 4);
      xgf[0] = bf2f(xv.x); xgf[1] = bf2f(xv.y); xgf[2] = bf2f(xv.z); xgf[3] = bf2f(xv.w);
    }

    // ---- barrier wait (per-group flag line) + acquire ----
    if (k < T_) {
      if (tid == 0) {
        unsigned spins = 0;
        while (__hip_atomic_load(&gflag[grp * 1024 + k], __ATOMIC_RELAXED, __HIP_MEMORY_SCOPE_AGENT) == 0u) {
          __builtin_amdgcn_s_sleep(1);
          if (++spins > 67108864u) break;   // safety: never wedge the GPU
        }
        __builtin_amdgcn_fence(__ATOMIC_ACQUIRE, "agent");
      }
      __syncthreads();
    }
  }

  // final cell states (rare, scattered is fine)
  if ((l & 3) == 0) {
    #pragma unroll
    for (int v = 0; v < 4; ++v)
      out[CS_OFF + layer * 65536 + (rbase + (l >> 4) * 4 + v) * 1024 + jg] = cr[v];
  }
}

extern "C" void kernel_launch(void* const* d_in, const int* in_sizes, int n_in,
                              void* d_out, int out_size, void* d_ws, size_t ws_size,
                              hipStream_t stream) {
  const float* x   = (const float*)d_in[0];
  const float* h0  = (const float*)d_in[1];
  const float* c0  = (const float*)d_in[2];
  const float* Wx0 = (const float*)d_in[3];
  const float* Wh0 = (const float*)d_in[4];
  const float* b0  = (const float*)d_in[5];
  const float* Wx1 = (const float*)d_in[6];
  const float* Wh1 = (const float*)d_in[7];
  const float* b1  = (const float*)d_in[8];
  float* out = (float*)d_out;
  char* ws = (char*)d_ws;
  if (ws_size < (size_t)WS_MIN) return;   // workspace too small -> fail loudly
  const int use_xg = (ws_size >= (size_t)WS_BIG) ? 1 : 0;

  unsigned* ctr       = (unsigned*)(ws + WS_CTR);
  unsigned short* wp  = (unsigned short*)(ws + WS_W);
  float* biasP        = (float*)(ws + WS_BIAS);
  unsigned short* xbp = (unsigned short*)(ws + WS_XB);
  unsigned short* h0r = (unsigned short*)(ws + WS_H0);
  unsigned short* h1r = (unsigned short*)(ws + WS_H1);
  unsigned short* xgp = (unsigned short*)(ws + WS_XG);

  (void)hipMemsetAsync(ctr, 0, 69632, stream);
  hipLaunchKernelGGL(kw,    dim3(4096),  dim3(256), 0, stream, Wx0, Wh0, Wx1, Wh1, wp);
  hipLaunchKernelGGL(kx,    dim3(32768), dim3(256), 0, stream, x, xbp);
  hipLaunchKernelGGL(kmisc, dim3(544),   dim3(256), 0, stream, b0, b1, h0, biasP, h0r, h1r);
  if (use_xg)
    hipLaunchKernelGGL(kxg, dim3(2048),  dim3(512), 0, stream, wp, xbp, xgp);

  (void)hipFuncSetAttribute((const void*)klstm, hipFuncAttributeMaxDynamicSharedMemorySize, 141312);
  const float* c0a = c0; const unsigned short* wpa = wp; const float* bpa = biasP;
  const unsigned short* xba = xbp; const unsigned short* xga = xgp;
  unsigned short* h0a = h0r; unsigned short* h1a = h1r;
  unsigned* ca = ctr; float* oa = out; int uxg = use_xg;
  void* args[] = {&c0a, &wpa, &bpa, &xba, &xga, &h0a, &h1a, &ca, &oa, &uxg};
  hipError_t e = hipLaunchCooperativeKernel((const void*)klstm, dim3(NBLK), dim3(TPB),
                                            args, 141312, stream);
  if (e != hipSuccess) {
    hipLaunchKernelGGL(klstm, dim3(NBLK), dim3(TPB), 141312, stream,
                       c0a, wpa, bpa, xba, xga, h0a, h1a, ca, oa, uxg);
  }
}

// Round 10
// 5768.360 us; speedup vs baseline: 1.5463x; 1.0228x over previous
//
#include <hip/hip_runtime.h>

// CustomLSTM on MI355X: persistent cooperative kernel (R6 skeleton), xg hoist,
// Wh pinned, tree barrier. R10: [oct][row][8] h-ring (single 16B A-loads, no
// repack) + acquire-inv moved to arrival (kills the L2 inv storm; post-flag
// h loads hit a once-per-XCD L2 refill).

#define NBLK 256
#define TPB  512
#define T_   512
#define HS_OFF 33554432   // outputs floats
#define CS_OFF 33685504   // HS_OFF + 2*64*1024

typedef float  f32x4  __attribute__((ext_vector_type(4)));
typedef short  bf16x8 __attribute__((ext_vector_type(8)));

// ---- workspace byte offsets ----
#define WS_CTR  0u              // 69632: gctr[8][1024] | rctr[1024] | gflag[8][1024]
#define WS_W    69632u          // 4 * (4096*1024) bf16 = 32 MiB (permuted, [m][p][k])
#define WS_BIAS 33624064u       // 2*4096 f32
#define WS_XB   33656832u       // [T][B][D] bf16 = 64 MiB
#define WS_H0   100765696u      // ring: 2 * 65536 bf16, layout [oct][row][8]
#define WS_H1   101027840u
#define WS_MIN  101289984u      // minimum ws (no xg)
#define WS_XG   101289984u      // [T][256][4][64][4] bf16 = 256 MiB
#define WS_BIG  369725440u

__device__ __forceinline__ unsigned short f2bf(float f) {
  union { float f; unsigned u; } v; v.f = f;
  return (unsigned short)((v.u + 0x7FFFu + ((v.u >> 16) & 1u)) >> 16);
}
__device__ __forceinline__ float bf2f(unsigned short s) {
  union { unsigned u; float f; } v; v.u = ((unsigned)s) << 16;
  return v.f;
}
__device__ __forceinline__ float fsig(float x) { return 1.0f / (1.0f + __expf(-x)); }
__device__ __forceinline__ float ftanh(float x) {
  x = fminf(15.0f, fmaxf(-15.0f, x));
  float e = __expf(2.0f * x);
  return (e - 1.0f) / (e + 1.0f);
}

// Permute+transpose+bf16 the 4 weight matrices: out[m][p][k] = bf16(W_m[k][orig(p)]),
// orig(p) = (p&3)*1024 + (p>>2)  (p = 4*j + gate). 64x64 tiles via LDS.
__global__ void kw(const float* __restrict__ Wx0, const float* __restrict__ Wh0,
                   const float* __restrict__ Wx1, const float* __restrict__ Wh1,
                   unsigned short* __restrict__ wp) {
  __shared__ float tile[64][65];
  int tb = blockIdx.x;
  int m  = tb >> 10;
  int kt = (tb >> 6) & 15;
  int nt = tb & 63;
  const float* W = (m == 0) ? Wx0 : (m == 1) ? Wh0 : (m == 2) ? Wx1 : Wh1;
  unsigned short* O = wp + (size_t)m * 4194304u;
  int k0 = kt * 64, n0 = nt * 64;
  int tx = threadIdx.x & 63, tg = threadIdx.x >> 6;
  for (int r = tg; r < 64; r += 4)
    tile[r][tx] = W[(size_t)(k0 + r) * 4096 + n0 + tx];
  __syncthreads();
  for (int r = tg; r < 64; r += 4) {
    int n = n0 + r;
    int p = ((n & 1023) << 2) | (n >> 10);
    O[(size_t)p * 1024 + k0 + tx] = f2bf(tile[tx][r]);
  }
}

// x [B][T][D] f32 -> xb [T*B][D] bf16 (row = t*64+b)
__global__ void kx(const float* __restrict__ x, unsigned short* __restrict__ xb) {
  int row = blockIdx.x;
  int t = row >> 6, b = row & 63;
  const float4* src = (const float4*)(x + ((size_t)b * 512 + t) * 1024);
  float4 f = src[threadIdx.x];
  ushort4 o; o.x = f2bf(f.x); o.y = f2bf(f.y); o.z = f2bf(f.z); o.w = f2bf(f.w);
  ((ushort4*)(xb + (size_t)row * 1024))[threadIdx.x] = o;
}

// bias permute + prime ring slot 1 with initial h states (bf16, [oct][row][8])
__global__ void kmisc(const float* __restrict__ b0, const float* __restrict__ b1,
                      const float* __restrict__ h0in,
                      float* __restrict__ biasP,
                      unsigned short* __restrict__ h0r, unsigned short* __restrict__ h1r) {
  int idx = blockIdx.x * 256 + threadIdx.x;
  if (idx < 8192) {
    int layer = idx >> 12, p = idx & 4095;
    int orig = (p & 3) * 1024 + (p >> 2);
    biasP[idx] = (layer ? b1 : b0)[orig];
  } else if (idx < 139264) {
    int e = idx - 8192;
    int layer = e >> 16, o = e & 65535;
    int row = o >> 10, col = o & 1023;
    unsigned short v = f2bf(h0in[layer * 65536 + o]);
    int dst = 65536 + (col >> 3) * 512 + row * 8 + (col & 7);
    if (layer) h1r[dst] = v; else h0r[dst] = v;
  }
}

// Pre-GEMM: xg[t][cb16][rt][lane][v] = (x[t] @ Wx0) fragment, finalize-lane layout.
// 2048 blocks = 128 col-blocks(32 cols) x 16 t-chunks(32 t). 8 waves = 4 rt x 2 kh.
__global__ void __launch_bounds__(512, 2)
kxg(const unsigned short* __restrict__ wp, const unsigned short* __restrict__ xb,
    unsigned short* __restrict__ xg) {
  __shared__ char sm[73728];                 // 64KB Wx0 slice + 8KB red
  float* red = (float*)(sm + 65536);
  const int tid = threadIdx.x;
  const int w = tid >> 6, l = tid & 63;
  const int cb = blockIdx.x >> 4;            // 32-col block, 0..127
  const int tc = blockIdx.x & 15;
  const int rt = w & 3, kh = w >> 2;

  const char* src = (const char*)(wp + (size_t)(cb * 32) * 1024u);
  for (int i = tid; i < 4096; i += 512) {
    int sb = i << 4;
    int c  = sb >> 11;
    int kb = sb & 2047;
    *(uint4*)(sm + (c << 11) + (kb ^ ((c & 7) << 4))) = *(const uint4*)(src + sb);
  }
  __syncthreads();

  const int ae0 = (rt * 16 + (l & 15)) * 1024 + kh * 512 + (l >> 4) * 8;
  const int kb2 = kh * 1024 + (l >> 4) * 16;
  const int swz = (l & 7) << 4;
  const int lb0 = (l & 15) << 11;
  const int lb1 = ((l & 15) + 16) << 11;

  for (int t = tc * 32; t < tc * 32 + 32; ++t) {
    const unsigned short* xt = xb + (size_t)t * 65536u;
    f32x4 a0 = {0.f, 0.f, 0.f, 0.f};
    f32x4 a1 = {0.f, 0.f, 0.f, 0.f};
    #pragma unroll
    for (int kk = 0; kk < 16; ++kk) {
      bf16x8 ax = *(const bf16x8*)(xt + ae0 + kk * 32);
      const int kb = (kb2 + kk * 64) ^ swz;
      bf16x8 b0 = *(const bf16x8*)(sm + lb0 + kb);
      bf16x8 b1 = *(const bf16x8*)(sm + lb1 + kb);
      a0 = __builtin_amdgcn_mfma_f32_16x16x32_bf16(ax, b0, a0, 0, 0, 0);
      a1 = __builtin_amdgcn_mfma_f32_16x16x32_bf16(ax, b1, a1, 0, 0, 0);
    }
    if (kh == 1) {
      float* r0 = red + (size_t)((rt * 2 + 0) * 64 + l) * 4;
      float* r1 = red + (size_t)((rt * 2 + 1) * 64 + l) * 4;
      #pragma unroll
      for (int v = 0; v < 4; ++v) { r0[v] = a0[v]; r1[v] = a1[v]; }
    }
    __syncthreads();
    if (kh == 0) {
      const float* r0 = red + (size_t)((rt * 2 + 0) * 64 + l) * 4;
      const float* r1 = red + (size_t)((rt * 2 + 1) * 64 + l) * 4;
      ushort4 o0, o1;
      o0.x = f2bf(a0[0] + r0[0]); o0.y = f2bf(a0[1] + r0[1]);
      o0.z = f2bf(a0[2] + r0[2]); o0.w = f2bf(a0[3] + r0[3]);
      o1.x = f2bf(a1[0] + r1[0]); o1.y = f2bf(a1[1] + r1[1]);
      o1.z = f2bf(a1[2] + r1[2]); o1.w = f2bf(a1[3] + r1[3]);
      *(ushort4*)(xg + ((((size_t)t * 256 + (cb * 2 + 0)) * 4 + rt) * 64 + l) * 4) = o0;
      *(ushort4*)(xg + ((((size_t)t * 256 + (cb * 2 + 1)) * 4 + rt) * 64 + l) * 4) = o1;
    }
    __syncthreads();
  }
}

// Persistent cooperative kernel. 256 blocks x 512 threads (8 waves).
// Wave w: rows 16*(w&3), K-half (w>>2)*512, finalizes layer (w>>2).
__global__ void __launch_bounds__(TPB)
klstm(const float* __restrict__ c0_in,
      const unsigned short* __restrict__ wp,
      const float* __restrict__ biasP,
      const unsigned short* __restrict__ xb,
      const unsigned short* __restrict__ xg,
      unsigned short* __restrict__ h0ring,
      unsigned short* __restrict__ h1ring,
      unsigned* __restrict__ ctrbase,
      float* __restrict__ out,
      int use_xg) {
  extern __shared__ char smem[];           // 64KB Wx + 8KB red + 2KB h-repack
  float* red = (float*)(smem + 131072);
  float* lhb = (float*)(smem + 139264);
  unsigned* gctr  = ctrbase;               // [8][1024]
  unsigned* rctr  = ctrbase + 8192;        // [1024]
  unsigned* gflag = ctrbase + 9216;        // [8][1024]
  const int tid = threadIdx.x;
  const int w   = tid >> 6;
  const int l   = tid & 63;
  const int bid = blockIdx.x;
  const int n0  = bid * 16;
  const int layer = w >> 2;
  const int rbase = (w & 3) * 16;
  const int khalf = (w >> 2) * 512;
  const int grp   = bid >> 5;
  float* lh = lhb + w * 64;                // [16 rows][4 cols] f32 per wave

  // stage Wx0 (m=0) and Wx1 (m=2) slices into LDS, XOR-swizzled
  for (int m = 0; m < 4; m += 2) {
    const char* src = (const char*)(wp + (size_t)m * 4194304u + (size_t)n0 * 1024u);
    char* dst = smem + m * 32768;
    for (int i = tid; i < 2048; i += TPB) {
      int sb = i << 4;
      int c  = sb >> 11;
      int kb = sb & 2047;
      *(uint4*)(dst + (c << 11) + (kb ^ ((c & 7) << 4))) = *(const uint4*)(src + sb);
    }
  }

  // pin Wh0 / Wh1 fragments (16 cols x this wave's K-half)
  bf16x8 wh0f[16], wh1f[16];
  {
    const unsigned short* p0 = wp + 4194304u + (size_t)(n0 + (l & 15)) * 1024u + khalf + (l >> 4) * 8;
    const unsigned short* p1 = wp + 3u * 4194304u + (size_t)(n0 + (l & 15)) * 1024u + khalf + (l >> 4) * 8;
    #pragma unroll
    for (int ks = 0; ks < 16; ++ks) {
      wh0f[ks] = *(const bf16x8*)(p0 + ks * 32);
      wh1f[ks] = *(const bf16x8*)(p1 + ks * 32);
    }
  }

  const int jg = bid * 4 + ((l & 15) >> 2);   // global h column (gate finalize)
  const float biasv = biasP[layer * 4096 + n0 + (l & 15)];
  const int qb = l & ~3;

  float cr[4];
  #pragma unroll
  for (int v = 0; v < 4; ++v)
    cr[v] = c0_in[layer * 65536 + (rbase + (l >> 4) * 4 + v) * 1024 + jg];
  __syncthreads();

  const int ae0  = (rbase + (l & 15)) * 1024 + khalf + (l >> 4) * 8;  // xb (row-major)
  // [oct][row][8] ring: A-fragment base; +2048 elements per kk
  const int hbase = ((khalf >> 3) + (l >> 4)) * 512 + (rbase + (l & 15)) * 8;
  const int lb0  = (l & 15) << 11;
  const int kb2  = khalf * 2 + (l >> 4) * 16;
  const int swz  = (l & 7) << 4;
  // h store address (8B per lane, l<16): oct bid>>1, row rbase+l, cols 4*(bid&1)..
  const int hsto = (bid >> 1) * 512 + 4 * (bid & 1);

  float xgf[4] = {0.f, 0.f, 0.f, 0.f};
  if (use_xg && w < 4) {
    ushort4 xv = *(const ushort4*)(xg + (((size_t)bid * 4 + w) * 64 + l) * 4);
    xgf[0] = bf2f(xv.x); xgf[1] = bf2f(xv.y); xgf[2] = bf2f(xv.z); xgf[3] = bf2f(xv.w);
  }

  for (int k = 0; k <= T_; ++k) {
    #pragma unroll
    for (int ks = 0; ks < 16; ++ks) {
      asm volatile("" :: "v"(wh0f[ks]));
      asm volatile("" :: "v"(wh1f[ks]));
    }

    const unsigned short* h0p = h0ring + ((k + 1) & 1) * 65536;
    const unsigned short* h1p = h1ring + (k & 1) * 65536;

    f32x4 acc0  = {0.f, 0.f, 0.f, 0.f};
    f32x4 acc0b = {0.f, 0.f, 0.f, 0.f};
    f32x4 acc1a = {0.f, 0.f, 0.f, 0.f};
    f32x4 acc1b = {0.f, 0.f, 0.f, 0.f};
    if (use_xg) {
      #pragma unroll
      for (int kk = 0; kk < 16; ++kk) {
        bf16x8 ah0 = *(const bf16x8*)(h0p + hbase + kk * 2048);
        bf16x8 ah1 = *(const bf16x8*)(h1p + hbase + kk * 2048);
        const int bo = lb0 + ((kb2 + kk * 64) ^ swz);
        bf16x8 bx1 = *(const bf16x8*)(smem + 65536 + bo);
        acc0  = __builtin_amdgcn_mfma_f32_16x16x32_bf16(ah0, wh0f[kk], acc0, 0, 0, 0);
        acc1a = __builtin_amdgcn_mfma_f32_16x16x32_bf16(ah0, bx1, acc1a, 0, 0, 0);
        acc1b = __builtin_amdgcn_mfma_f32_16x16x32_bf16(ah1, wh1f[kk], acc1b, 0, 0, 0);
      }
    } else {
      const unsigned short* xt = xb + (size_t)((k < T_) ? k : (T_ - 1)) * 65536u;
      #pragma unroll
      for (int kk = 0; kk < 16; ++kk) {
        bf16x8 ax  = *(const bf16x8*)(xt + ae0 + kk * 32);
        bf16x8 ah0 = *(const bf16x8*)(h0p + hbase + kk * 2048);
        bf16x8 ah1 = *(const bf16x8*)(h1p + hbase + kk * 2048);
        const int bo = lb0 + ((kb2 + kk * 64) ^ swz);
        bf16x8 bx0 = *(const bf16x8*)(smem + bo);
        bf16x8 bx1 = *(const bf16x8*)(smem + 65536 + bo);
        acc0b = __builtin_amdgcn_mfma_f32_16x16x32_bf16(ax,  bx0, acc0b, 0, 0, 0);
        acc0  = __builtin_amdgcn_mfma_f32_16x16x32_bf16(ah0, wh0f[kk], acc0, 0, 0, 0);
        acc1a = __builtin_amdgcn_mfma_f32_16x16x32_bf16(ah0, bx1, acc1a, 0, 0, 0);
        acc1b = __builtin_amdgcn_mfma_f32_16x16x32_bf16(ah1, wh1f[kk], acc1b, 0, 0, 0);
      }
    }

    { // publish the other layer's partial for the partner wave
      float* rb = red + (size_t)(w * 64 + l) * 4;
      f32x4 other = layer ? (acc0 + acc0b) : (acc1a + acc1b);
      #pragma unroll
      for (int v = 0; v < 4; ++v) rb[v] = other[v];
    }
    __syncthreads();

    f32x4 g = layer ? (acc1a + acc1b) : (acc0 + acc0b);
    {
      const int pw = layer ? (w - 4) : (w + 4);
      const float* rb = red + (size_t)(pw * 64 + l) * 4;
      #pragma unroll
      for (int v = 0; v < 4; ++v) g[v] += rb[v];
    }
    if (use_xg && w < 4) {
      #pragma unroll
      for (int v = 0; v < 4; ++v) g[v] += xgf[v];
    }

    const bool active = layer ? (k >= 1) : (k < T_);
    f32x4 outv = {0.f, 0.f, 0.f, 0.f};
    if (active) {
      unsigned short* hw = layer ? (h1ring + ((k + 1) & 1) * 65536)
                                 : (h0ring + (k & 1) * 65536);
      #pragma unroll
      for (int v = 0; v < 4; ++v) {
        float gv = g[v] + biasv;
        float gi = __shfl(gv, qb);
        float gf = __shfl(gv, qb | 1);
        float gn = __shfl(gv, qb | 2);
        float go = __shfl(gv, qb | 3);
        float i_ = fsig(gi), f_ = fsig(gf), n_ = ftanh(gn), o_ = fsig(go);
        float c = f_ * cr[v] + i_ * n_;
        cr[v] = c;
        float h = o_ * ftanh(c);
        if ((l & 3) == 0)
          lh[((l >> 4) * 4 + v) * 4 + ((l & 15) >> 2)] = h;   // repack tile
      }
      if (l < 16) {   // same-wave read-back: coalesced 8B agent store
        f32x4 h4 = *(f32x4*)(lh + l * 4);
        outv = h4;
        ushort4 u4;
        u4.x = f2bf(h4[0]); u4.y = f2bf(h4[1]); u4.z = f2bf(h4[2]); u4.w = f2bf(h4[3]);
        union { ushort4 s; unsigned long long q; } pk; pk.s = u4;
        __hip_atomic_store((unsigned long long*)(hw + hsto + (rbase + l) * 8), pk.q,
                           __ATOMIC_RELAXED, __HIP_MEMORY_SCOPE_AGENT);
      }
    }

    // ---- barrier arrival + EARLY acquire-inv (off the critical path) ----
    if (k < T_) {
      __syncthreads();                      // drain h stores block-wide
      if (tid == 0) {
        unsigned old = __hip_atomic_fetch_add(&gctr[grp * 1024 + k], 1u,
                                              __ATOMIC_RELAXED, __HIP_MEMORY_SCOPE_AGENT);
        if (old == 31u) {
          unsigned oldr = __hip_atomic_fetch_add(&rctr[k], 1u,
                                                 __ATOMIC_RELAXED, __HIP_MEMORY_SCOPE_AGENT);
          if (oldr == 7u) {
            #pragma unroll
            for (int gg = 0; gg < 8; ++gg)
              __hip_atomic_store(&gflag[gg * 1024 + k], 1u,
                                 __ATOMIC_RELAXED, __HIP_MEMORY_SCOPE_AGENT);
          }
        }
        // invalidate NOW: all 32 invs/XCD complete before the flag can set,
        // so post-flag h loads refill L2 once per XCD (no inv storm).
        __builtin_amdgcn_fence(__ATOMIC_ACQUIRE, "agent");
      }
    }

    // ---- overlap window: deferred out stores + next-step xg prefetch ----
    if (active && l < 16) {
      const int row = rbase + l;
      if (layer) {
        *(f32x4*)(out + (size_t)row * 524288u + (size_t)(k - 1) * 1024u + bid * 4) = outv;
        if (k == T_)
          *(f32x4*)(out + HS_OFF + 65536 + row * 1024 + bid * 4) = outv;
      } else if (k == T_ - 1) {
        *(f32x4*)(out + HS_OFF + row * 1024 + bid * 4) = outv;
      }
    }
    if (use_xg && w < 4 && k + 1 < T_) {   // registers survive; reads are fresh misses
      ushort4 xv = *(const ushort4*)(xg + ((((size_t)(k + 1) * 256 + bid) * 4 + w) * 64 + l) * 4);
      xgf[0] = bf2f(xv.x); xgf[1] = bf2f(xv.y); xgf[2] = bf2f(xv.z); xgf[3] = bf2f(xv.w);
    }

    // ---- barrier wait (per-group flag line); syncthreads = ordering fence ----
    if (k < T_) {
      if (tid == 0) {
        unsigned spins = 0;
        while (__hip_atomic_load(&gflag[grp * 1024 + k], __ATOMIC_RELAXED, __HIP_MEMORY_SCOPE_AGENT) == 0u) {
          __builtin_amdgcn_s_sleep(1);
          if (++spins > 67108864u) break;   // safety: never wedge the GPU
        }
      }
      __syncthreads();
    }
  }

  // final cell states (rare, scattered is fine)
  if ((l & 3) == 0) {
    #pragma unroll
    for (int v = 0; v < 4; ++v)
      out[CS_OFF + layer * 65536 + (rbase + (l >> 4) * 4 + v) * 1024 + jg] = cr[v];
  }
}

extern "C" void kernel_launch(void* const* d_in, const int* in_sizes, int n_in,
                              void* d_out, int out_size, void* d_ws, size_t ws_size,
                              hipStream_t stream) {
  const float* x   = (const float*)d_in[0];
  const float* h0  = (const float*)d_in[1];
  const float* c0  = (const float*)d_in[2];
  const float* Wx0 = (const float*)d_in[3];
  const float* Wh0 = (const float*)d_in[4];
  const float* b0  = (const float*)d_in[5];
  const float* Wx1 = (const float*)d_in[6];
  const float* Wh1 = (const float*)d_in[7];
  const float* b1  = (const float*)d_in[8];
  float* out = (float*)d_out;
  char* ws = (char*)d_ws;
  if (ws_size < (size_t)WS_MIN) return;   // workspace too small -> fail loudly
  const int use_xg = (ws_size >= (size_t)WS_BIG) ? 1 : 0;

  unsigned* ctr       = (unsigned*)(ws + WS_CTR);
  unsigned short* wp  = (unsigned short*)(ws + WS_W);
  float* biasP        = (float*)(ws + WS_BIAS);
  unsigned short* xbp = (unsigned short*)(ws + WS_XB);
  unsigned short* h0r = (unsigned short*)(ws + WS_H0);
  unsigned short* h1r = (unsigned short*)(ws + WS_H1);
  unsigned short* xgp = (unsigned short*)(ws + WS_XG);

  (void)hipMemsetAsync(ctr, 0, 69632, stream);
  hipLaunchKernelGGL(kw,    dim3(4096),  dim3(256), 0, stream, Wx0, Wh0, Wx1, Wh1, wp);
  hipLaunchKernelGGL(kx,    dim3(32768), dim3(256), 0, stream, x, xbp);
  hipLaunchKernelGGL(kmisc, dim3(544),   dim3(256), 0, stream, b0, b1, h0, biasP, h0r, h1r);
  if (use_xg)
    hipLaunchKernelGGL(kxg, dim3(2048),  dim3(512), 0, stream, wp, xbp, xgp);

  (void)hipFuncSetAttribute((const void*)klstm, hipFuncAttributeMaxDynamicSharedMemorySize, 141312);
  const float* c0a = c0; const unsigned short* wpa = wp; const float* bpa = biasP;
  const unsigned short* xba = xbp; const unsigned short* xga = xgp;
  unsigned short* h0a = h0r; unsigned short* h1a = h1r;
  unsigned* ca = ctr; float* oa = out; int uxg = use_xg;
  void* args[] = {&c0a, &wpa, &bpa, &xba, &xga, &h0a, &h1a, &ca, &oa, &uxg};
  hipError_t e = hipLaunchCooperativeKernel((const void*)klstm, dim3(NBLK), dim3(TPB),
                                            args, 141312, stream);
  if (e != hipSuccess) {
    hipLaunchKernelGGL(klstm, dim3(NBLK), dim3(TPB), 141312, stream,
                       c0a, wpa, bpa, xba, xga, h0a, h1a, ca, oa, uxg);
  }
}